// Round 1
// baseline (1361.263 us; speedup 1.0000x reference)
//
#include <hip/hip_runtime.h>
#include <math.h>

#define BB 32
#define LL 4096
#define HH 512
#define TILE_L 32

// ---------------------------------------------------------------------------
// prep: base[b][o] = sum_h query[b,h]*Wq[o,h] + bias[o] + conv_b[o]
// grid 64 (= B*2 chunks of 256 outputs), block 256
// ---------------------------------------------------------------------------
__global__ __launch_bounds__(256) void prep_kernel(
    const float* __restrict__ query, const float* __restrict__ Wq,
    const float* __restrict__ bias, const float* __restrict__ conv_b,
    float* __restrict__ base) {
  const int b = blockIdx.x >> 1;
  const int o = ((blockIdx.x & 1) << 8) + threadIdx.x;
  __shared__ float qrow[HH];
  for (int i = threadIdx.x; i < HH; i += 256) qrow[i] = query[b * HH + i];
  __syncthreads();
  const float* wq = Wq + (size_t)o * HH;
  float acc = 0.f;
  for (int h = 0; h < HH; h += 4) {
    float4 w = *(const float4*)(wq + h);
    acc += w.x * qrow[h] + w.y * qrow[h + 1] + w.z * qrow[h + 2] + w.w * qrow[h + 3];
  }
  base[b * HH + o] = acc + bias[o] + conv_b[o];
}

// ---------------------------------------------------------------------------
// main: per block: one batch b, TILE_L=32 rows.
//  - stage value tile (32x512 f32, 64 KiB) in LDS
//  - each thread owns o0=tid, o1=tid+256; register-blocks 32 row accumulators
//  - v[l,o] = dot(value[l,:], Wv[o,:]);  e = tanh(v + base + conv);  wave+LDS
//    reduce sum_o e*Ws[o]; sigmoid -> s written (unnormalized) to attn out
//  - context partial: sum_l s[l]*value[l][o] -> atomicAdd into ws ctx
// grid (L/TILE_L, B) = (128, 32), block 256
// ---------------------------------------------------------------------------
__global__ __launch_bounds__(256) void main_kernel(
    const float* __restrict__ value, const float* __restrict__ last_attn,
    const float* __restrict__ conv_w, const float* __restrict__ Wv,
    const float* __restrict__ Ws, const float* __restrict__ bs,
    const float* __restrict__ base, float* __restrict__ ctx,
    float* __restrict__ attn) {
  const int b = blockIdx.y;
  const int l0 = blockIdx.x * TILE_L;
  const int tid = threadIdx.x;

  __shared__ float val[TILE_L][HH];   // 64 KiB
  __shared__ float la[TILE_L + 2];
  __shared__ float red[4][TILE_L];
  __shared__ float srow[TILE_L];

  // ---- stage value tile (contiguous 32*512 floats) ----
  {
    const float4* src4 = (const float4*)(value + ((size_t)b * LL + l0) * HH);
    float4* dst4 = (float4*)&val[0][0];
    #pragma unroll
    for (int i = 0; i < (TILE_L * HH / 4) / 256; ++i)
      dst4[tid + i * 256] = src4[tid + i * 256];
  }
  if (tid < TILE_L + 2) {
    int l = l0 - 1 + tid;
    la[tid] = (l >= 0 && l < LL) ? last_attn[b * LL + l] : 0.f;
  }
  __syncthreads();

  const int o0 = tid, o1 = tid + 256;
  float acc0[TILE_L], acc1[TILE_L];
  #pragma unroll
  for (int l = 0; l < TILE_L; ++l) { acc0[l] = 0.f; acc1[l] = 0.f; }

  // ---- projection GEMM: acc[l] += value[l][h..h+3] . Wv[o][h..h+3] ----
  const float* wv0 = Wv + (size_t)o0 * HH;
  const float* wv1 = Wv + (size_t)o1 * HH;
  float4 w0 = *(const float4*)(wv0);
  float4 w1 = *(const float4*)(wv1);
  for (int h = 0; h < HH; h += 4) {
    const int hn = (h + 4 < HH) ? h + 4 : 0;   // prefetch next Wv chunk
    float4 nw0 = *(const float4*)(wv0 + hn);
    float4 nw1 = *(const float4*)(wv1 + hn);
    #pragma unroll
    for (int l = 0; l < TILE_L; ++l) {
      float4 v = *(const float4*)(&val[l][h]);   // same addr all lanes: broadcast
      acc0[l] += v.x * w0.x + v.y * w0.y + v.z * w0.z + v.w * w0.w;
      acc1[l] += v.x * w1.x + v.y * w1.y + v.z * w1.z + v.w * w1.w;
    }
    w0 = nw0; w1 = nw1;
  }

  // ---- epilogue: conv + tanh + Ws dot, reduce over o ----
  const float b0 = base[b * HH + o0];
  const float b1 = base[b * HH + o1];
  const float cw00 = conv_w[o0 * 3 + 0], cw01 = conv_w[o0 * 3 + 1], cw02 = conv_w[o0 * 3 + 2];
  const float cw10 = conv_w[o1 * 3 + 0], cw11 = conv_w[o1 * 3 + 1], cw12 = conv_w[o1 * 3 + 2];
  const float s0 = Ws[o0], s1 = Ws[o1];
  #pragma unroll
  for (int l = 0; l < TILE_L; ++l) {
    float c0 = b0 + cw00 * la[l] + cw01 * la[l + 1] + cw02 * la[l + 2];
    float c1 = b1 + cw10 * la[l] + cw11 * la[l + 1] + cw12 * la[l + 2];
    float e = tanhf(acc0[l] + c0) * s0 + tanhf(acc1[l] + c1) * s1;
    #pragma unroll
    for (int off = 32; off > 0; off >>= 1) e += __shfl_xor(e, off, 64);
    if ((tid & 63) == 0) red[tid >> 6][l] = e;
  }
  __syncthreads();
  if (tid < TILE_L) {
    float sc = red[0][tid] + red[1][tid] + red[2][tid] + red[3][tid] + bs[0];
    float s = 1.f / (1.f + expf(-sc));
    srow[tid] = s;
    attn[b * LL + l0 + tid] = s;    // unnormalized; finalize divides by S
  }
  __syncthreads();

  // ---- context partial: sum_l s[l] * value[l][o] ----
  float c0 = 0.f, c1 = 0.f;
  #pragma unroll
  for (int l = 0; l < TILE_L; ++l) {
    float s = srow[l];
    c0 += s * val[l][o0];
    c1 += s * val[l][o1];
  }
  atomicAdd(&ctx[b * HH + o0], c0);
  atomicAdd(&ctx[b * HH + o1], c1);
}

// ---------------------------------------------------------------------------
// finalize: per batch: S = sum_l s; attn /= S; out = [ctx/S, query]
// grid B, block 512
// ---------------------------------------------------------------------------
__global__ __launch_bounds__(512) void finalize_kernel(
    const float* __restrict__ query, const float* __restrict__ ctx,
    float* __restrict__ out, float* __restrict__ attn) {
  const int b = blockIdx.x;
  const int tid = threadIdx.x;
  __shared__ float red[8];
  float s = 0.f;
  for (int l = tid; l < LL; l += 512) s += attn[b * LL + l];
  #pragma unroll
  for (int off = 32; off > 0; off >>= 1) s += __shfl_xor(s, off, 64);
  if ((tid & 63) == 0) red[tid >> 6] = s;
  __syncthreads();
  float S = 0.f;
  #pragma unroll
  for (int i = 0; i < 8; ++i) S += red[i];
  const float inv = 1.f / S;
  out[b * 2 * HH + tid] = ctx[b * HH + tid] * inv;
  out[b * 2 * HH + HH + tid] = query[b * HH + tid];
  for (int l = tid; l < LL; l += 512) attn[b * LL + l] *= inv;
}

// ---------------------------------------------------------------------------
extern "C" void kernel_launch(void* const* d_in, const int* in_sizes, int n_in,
                              void* d_out, int out_size, void* d_ws, size_t ws_size,
                              hipStream_t stream) {
  const float* query     = (const float*)d_in[0];
  const float* value     = (const float*)d_in[1];
  const float* last_attn = (const float*)d_in[2];
  const float* conv_w    = (const float*)d_in[3];
  const float* conv_b    = (const float*)d_in[4];
  const float* Wq        = (const float*)d_in[5];
  const float* Wv        = (const float*)d_in[6];
  const float* Ws        = (const float*)d_in[7];
  const float* bs        = (const float*)d_in[8];
  const float* bias      = (const float*)d_in[9];

  float* out  = (float*)d_out;            // (B, 2H)
  float* attn = out + BB * 2 * HH;        // (B, L)
  float* base = (float*)d_ws;             // B*H
  float* ctx  = base + BB * HH;           // B*H  (atomic accumulators)

  hipMemsetAsync(ctx, 0, BB * HH * sizeof(float), stream);
  prep_kernel<<<64, 256, 0, stream>>>(query, Wq, bias, conv_b, base);
  dim3 grid(LL / TILE_L, BB);
  main_kernel<<<grid, 256, 0, stream>>>(value, last_attn, conv_w, Wv, Ws, bs,
                                        base, ctx, attn);
  finalize_kernel<<<BB, 512, 0, stream>>>(query, ctx, out, attn);
}

// Round 2
// 211.991 us; speedup vs baseline: 6.4213x; 6.4213x over previous
//
#include <hip/hip_runtime.h>
#include <hip/hip_bf16.h>
#include <math.h>

#define BB 32
#define LL 4096
#define HH 512
#define TM 64    // rows per block tile

typedef __attribute__((ext_vector_type(8))) short short8;
typedef __attribute__((ext_vector_type(8))) unsigned short u16x8;
typedef __attribute__((ext_vector_type(4))) float f32x4;

__device__ __forceinline__ unsigned short f2bf(float f) {
  __hip_bfloat16 h = __float2bfloat16(f);
  unsigned short u;
  __builtin_memcpy(&u, &h, 2);
  return u;
}
__device__ __forceinline__ float bf2f(unsigned short u) {
  unsigned int x = ((unsigned int)u) << 16;
  float f;
  __builtin_memcpy(&f, &x, 4);
  return f;
}
__device__ __forceinline__ float fast_tanh(float x) {
  float e = __expf(2.f * x);
  return 1.f - 2.f / (e + 1.f);
}

// ---------------------------------------------------------------------------
// prep_base: base[b][o] = query[b,:].Wq[o,:] + bias[o] + conv_b[o]
// grid 64 (b*2 halves), block 256
// ---------------------------------------------------------------------------
__global__ __launch_bounds__(256) void prep_base(
    const float* __restrict__ query, const float* __restrict__ Wq,
    const float* __restrict__ bias, const float* __restrict__ conv_b,
    float* __restrict__ base) {
  const int b = blockIdx.x >> 1;
  const int o = ((blockIdx.x & 1) << 8) + threadIdx.x;
  __shared__ float qrow[HH];
  for (int i = threadIdx.x; i < HH; i += 256) qrow[i] = query[b * HH + i];
  __syncthreads();
  const float* wq = Wq + (size_t)o * HH;
  float acc = 0.f;
  for (int h = 0; h < HH; h += 4) {
    float4 w = *(const float4*)(wq + h);
    acc += w.x * qrow[h] + w.y * qrow[h + 1] + w.z * qrow[h + 2] + w.w * qrow[h + 3];
  }
  base[b * HH + o] = acc + bias[o] + conv_b[o];
}

// ---------------------------------------------------------------------------
// prep_wv: gather Wv (f32, [o][h]) into fragment-ordered bf16:
//   wvf[((nb*16 + kk)*64 + lane)*8 + j] = bf16(Wv[nb*16 + (lane&15)][kk*32 + (lane>>4)*8 + j])
// so a wave's b_frag load for (nb,kk) is one contiguous, coalesced 1024 B.
// 32768 chunks; grid 128, block 256
// ---------------------------------------------------------------------------
__global__ __launch_bounds__(256) void prep_wv(const float* __restrict__ Wv,
                                               unsigned short* __restrict__ wvf) {
  const int chunk = blockIdx.x * 256 + threadIdx.x;
  const int l = chunk & 63;
  const int kk = (chunk >> 6) & 15;
  const int nb = chunk >> 10;
  const int row = nb * 16 + (l & 15);
  const int colf = kk * 32 + (l >> 4) * 8;
  const float* src = Wv + (size_t)row * HH + colf;
  u16x8 v;
  #pragma unroll
  for (int j = 0; j < 8; ++j) v[j] = f2bf(src[j]);
  *(u16x8*)(wvf + (size_t)chunk * 8) = v;
}

// ---------------------------------------------------------------------------
// main: block = one (b, 64-row tile). 512 threads = 8 waves, wave w owns
// cols [w*64, w*64+64). Full K=512 value tile staged bf16 in LDS (swizzled).
//  MFMA 16x16x32 -> fused conv+tanh+Ws reduce -> sigmoid -> unnorm s ->
//  context partials from LDS tile -> atomicAdd.
// grid (64, 32), block 512
// ---------------------------------------------------------------------------
__global__ __launch_bounds__(512, 4) void main_kernel(
    const float* __restrict__ value, const float* __restrict__ last_attn,
    const float* __restrict__ conv_w, const unsigned short* __restrict__ wvf,
    const float* __restrict__ Ws, const float* __restrict__ bs,
    const float* __restrict__ base, float* __restrict__ ctx,
    float* __restrict__ attn) {
  const int b = blockIdx.y;
  const int l0 = blockIdx.x * TM;
  const int tid = threadIdx.x;
  const int w = tid >> 6;
  const int lane = tid & 63;

  __shared__ __align__(16) unsigned short A[TM * HH];  // 64 KiB, XOR-swizzled
  __shared__ float la_s[TM + 2];
  __shared__ float scorered[8][TM];
  __shared__ float srow[TM];

  char* Ab = (char*)A;

  // ---- stage value tile: f32 -> bf16, swizzled LDS ----
  const float* vsrc = value + (size_t)(b * LL + l0) * HH;
  #pragma unroll
  for (int i = 0; i < 8; ++i) {
    const int c = tid + i * 512;        // chunk: 8 bf16
    const int row = c >> 6;
    const int cb = c & 63;
    const float4* s4 = (const float4*)(vsrc + (size_t)row * HH + cb * 8);
    float4 lo = s4[0], hi = s4[1];
    u16x8 v;
    v[0] = f2bf(lo.x); v[1] = f2bf(lo.y); v[2] = f2bf(lo.z); v[3] = f2bf(lo.w);
    v[4] = f2bf(hi.x); v[5] = f2bf(hi.y); v[6] = f2bf(hi.z); v[7] = f2bf(hi.w);
    const int off = row * 1024 + ((cb * 16) ^ ((row & 7) << 4));
    *(u16x8*)(Ab + off) = v;
  }
  if (tid < TM + 2) {
    int l = l0 - 1 + tid;
    la_s[tid] = (l >= 0 && l < LL) ? last_attn[b * LL + l] : 0.f;
  }
  __syncthreads();

  // ---- MFMA: acc[m][n] over K=512 (16 K-steps of 32) ----
  f32x4 acc[4][4] = {};
  const int g = lane >> 4;
  const int r16 = lane & 15;

  short8 bcur[4], bnxt[4];
  #pragma unroll
  for (int n = 0; n < 4; ++n)
    bcur[n] = *(const short8*)(wvf + ((size_t)((w * 4 + n) * 16 + 0) * 64 + lane) * 8);

  for (int kk = 0; kk < 16; ++kk) {
    if (kk < 15) {
      #pragma unroll
      for (int n = 0; n < 4; ++n)
        bnxt[n] = *(const short8*)(wvf + ((size_t)((w * 4 + n) * 16 + kk + 1) * 64 + lane) * 8);
    }
    #pragma unroll
    for (int m = 0; m < 4; ++m) {
      const int row = m * 16 + r16;
      const int off = row * 1024 + ((kk * 64 + g * 16) ^ ((row & 7) << 4));
      short8 a = *(const short8*)(Ab + off);
      #pragma unroll
      for (int n = 0; n < 4; ++n)
        acc[m][n] = __builtin_amdgcn_mfma_f32_16x16x32_bf16(a, bcur[n], acc[m][n], 0, 0, 0);
    }
    #pragma unroll
    for (int n = 0; n < 4; ++n) bcur[n] = bnxt[n];
  }

  // ---- epilogue: e = tanh(acc + base + conv), rowsum += e*Ws ----
  float basev[4], wsv[4], cw0[4], cw1[4], cw2[4];
  #pragma unroll
  for (int n = 0; n < 4; ++n) {
    const int col = w * 64 + n * 16 + r16;
    basev[n] = base[b * HH + col];
    wsv[n] = Ws[col];
    cw0[n] = conv_w[col * 3 + 0];
    cw1[n] = conv_w[col * 3 + 1];
    cw2[n] = conv_w[col * 3 + 2];
  }
  #pragma unroll
  for (int m = 0; m < 4; ++m) {
    #pragma unroll
    for (int j = 0; j < 4; ++j) {
      const int row = m * 16 + g * 4 + j;
      const float lam = la_s[row], laz = la_s[row + 1], lap = la_s[row + 2];
      float sum = 0.f;
      #pragma unroll
      for (int n = 0; n < 4; ++n) {
        float e = acc[m][n][j] + basev[n] + cw0[n] * lam + cw1[n] * laz + cw2[n] * lap;
        sum += fast_tanh(e) * wsv[n];
      }
      sum += __shfl_xor(sum, 1, 64);
      sum += __shfl_xor(sum, 2, 64);
      sum += __shfl_xor(sum, 4, 64);
      sum += __shfl_xor(sum, 8, 64);
      if (r16 == 0) scorered[w][row] = sum;
    }
  }
  __syncthreads();
  if (tid < TM) {
    float sc = bs[0];
    #pragma unroll
    for (int ww = 0; ww < 8; ++ww) sc += scorered[ww][tid];
    float s = 1.f / (1.f + __expf(-sc));
    srow[tid] = s;
    attn[b * LL + l0 + tid] = s;   // unnormalized; finalize divides by S
  }
  __syncthreads();

  // ---- context partials: ctx[o] += sum_row s[row]*val[row][o] ----
  const int rg = tid & 7;          // row group
  const int cc = tid >> 3;         // col chunk (8 cols)
  float cs[8];
  #pragma unroll
  for (int k = 0; k < 8; ++k) cs[k] = 0.f;
  #pragma unroll
  for (int i = 0; i < 8; ++i) {
    const int row = rg * 8 + i;
    const int off = row * 1024 + ((cc * 16) ^ ((row & 7) << 4));
    u16x8 v = *(const u16x8*)(Ab + off);
    const float s = srow[row];
    #pragma unroll
    for (int k = 0; k < 8; ++k) cs[k] += s * bf2f(v[k]);
  }
  #pragma unroll
  for (int o = 1; o < 8; o <<= 1) {
    #pragma unroll
    for (int k = 0; k < 8; ++k) cs[k] += __shfl_xor(cs[k], o, 64);
  }
  if (rg == 0) {
    #pragma unroll
    for (int k = 0; k < 8; ++k) atomicAdd(&ctx[b * HH + cc * 8 + k], cs[k]);
  }
}

// ---------------------------------------------------------------------------
// finalize: per batch: S = sum_l s; attn /= S; out = [ctx/S, query]
// grid B, block 512
// ---------------------------------------------------------------------------
__global__ __launch_bounds__(512) void finalize_kernel(
    const float* __restrict__ query, const float* __restrict__ ctx,
    float* __restrict__ out, float* __restrict__ attn) {
  const int b = blockIdx.x;
  const int tid = threadIdx.x;
  __shared__ float red[8];
  float s = 0.f;
  for (int l = tid; l < LL; l += 512) s += attn[b * LL + l];
  #pragma unroll
  for (int off = 32; off > 0; off >>= 1) s += __shfl_xor(s, off, 64);
  if ((tid & 63) == 0) red[tid >> 6] = s;
  __syncthreads();
  float S = 0.f;
  #pragma unroll
  for (int i = 0; i < 8; ++i) S += red[i];
  const float inv = 1.f / S;
  out[b * 2 * HH + tid] = ctx[b * HH + tid] * inv;
  out[b * 2 * HH + HH + tid] = query[b * HH + tid];
  for (int l = tid; l < LL; l += 512) attn[b * LL + l] *= inv;
}

// ---------------------------------------------------------------------------
extern "C" void kernel_launch(void* const* d_in, const int* in_sizes, int n_in,
                              void* d_out, int out_size, void* d_ws, size_t ws_size,
                              hipStream_t stream) {
  const float* query     = (const float*)d_in[0];
  const float* value     = (const float*)d_in[1];
  const float* last_attn = (const float*)d_in[2];
  const float* conv_w    = (const float*)d_in[3];
  const float* conv_b    = (const float*)d_in[4];
  const float* Wq        = (const float*)d_in[5];
  const float* Wv        = (const float*)d_in[6];
  const float* Ws        = (const float*)d_in[7];
  const float* bs        = (const float*)d_in[8];
  const float* bias      = (const float*)d_in[9];

  float* out  = (float*)d_out;                 // (B, 2H)
  float* attn = out + BB * 2 * HH;             // (B, L)
  float* base = (float*)d_ws;                  // B*H f32
  float* ctx  = base + BB * HH;                // B*H f32 (atomic accum)
  unsigned short* wvf = (unsigned short*)(ctx + BB * HH);  // 512*512 bf16, frag-ordered

  hipMemsetAsync(ctx, 0, BB * HH * sizeof(float), stream);
  prep_base<<<64, 256, 0, stream>>>(query, Wq, bias, conv_b, base);
  prep_wv<<<128, 256, 0, stream>>>(Wv, wvf);
  dim3 grid(LL / TM, BB);
  main_kernel<<<grid, 512, 0, stream>>>(value, last_attn, conv_w, wvf, Ws, bs,
                                        base, ctx, attn);
  finalize_kernel<<<BB, 512, 0, stream>>>(query, ctx, out, attn);
}